// Round 16
// baseline (317.196 us; speedup 1.0000x reference)
//
#include <hip/hip_runtime.h>
#include <stdint.h>

typedef unsigned short u16;
typedef unsigned int u32;
typedef _Float16 f16;
typedef float v4f __attribute__((ext_vector_type(4)));
typedef f16 v8h __attribute__((ext_vector_type(8)));

#define CC 256
#define NNN 4096

__device__ __forceinline__ u16 f2h(float f) {
  union { f16 h; u16 u; } c; c.h = (f16)f; return c.u;
}
__device__ __forceinline__ float h2f(u16 u) {
  union { f16 h; u16 u; } c; c.u = u; return (float)c.h;
}
// monotone float<->uint encoding for atomicMax on fp32
__device__ __forceinline__ u32 encf(float f) {
  u32 u = __float_as_uint(f);
  return (u >> 31) ? ~u : (u | 0x80000000u);
}
__device__ __forceinline__ float decf(u32 u) {
  return (u >> 31) ? __uint_as_float(u & 0x7fffffffu) : __uint_as_float(~u);
}
__device__ __forceinline__ void async16(const void* g, void* l) {
  __builtin_amdgcn_global_load_lds(
      (const __attribute__((address_space(1))) uint32_t*)g,
      (__attribute__((address_space(3))) uint32_t*)l, 16, 0, 0);
}

// ---- W [256][256] fp32 -> Ws [256][256] single fp16, K(c)-fast ----
__global__ __launch_bounds__(256) void wsplit(const float* __restrict__ W,
                                              u16* __restrict__ Ws) {
  const int d = blockIdx.x, c = threadIdx.x;
  Ws[d * 256 + c] = f2h(W[d * 256 + c]);
}

// ---- both inputs, all batches: in [C][N] fp32 -> T [N][256] fp16
// (transposed) and Cb [C][N] fp16 copy. z = batch(0..3) | which<<2. ----
__global__ __launch_bounds__(256) void tsplit(
    const float* __restrict__ asrc, const float* __restrict__ bsrc,
    u16* __restrict__ aT, u16* __restrict__ bT,
    u16* __restrict__ aCb, u16* __restrict__ bCb) {
  __shared__ u16 th[64][65];
  const int bz = blockIdx.z;
  const int bb = bz & 3;
  const int wh = bz >> 2;
  const int n0 = blockIdx.x * 64;
  const int c0 = blockIdx.y * 64;
  const int tx = threadIdx.x & 63;
  const int ty = threadIdx.x >> 6;  // 0..3
  const float* ib = (wh ? bsrc : asrc) + (size_t)bb * CC * NNN;
  u16* Tb = (wh ? bT : aT) + (size_t)bb * NNN * 256;
  u16* Cbb = (wh ? bCb : aCb) + (size_t)bb * CC * NNN;
#pragma unroll
  for (int k = 0; k < 16; k++) {
    int r = ty + k * 4;
    float v = ib[(size_t)(c0 + r) * NNN + n0 + tx];
    u16 h = f2h(v);
    th[r][tx] = h;
    Cbb[(size_t)(c0 + r) * NNN + n0 + tx] = h;
  }
  __syncthreads();
#pragma unroll
  for (int k = 0; k < 16; k++) {
    int r = ty + k * 4;
    Tb[(size_t)(n0 + r) * 256 + c0 + tx] = th[tx][r];
  }
}

// ---- TN GEMM over fp16, K=256. BK=64, XOR-swizzled LDS.
// MODE 0: out = a~ single fp16, pitch 256.
// MODE 1: out = S fp16 + row/col max atomics; per-z batch slabs;
//         tiles XCD-clustered in xy.
template <int MODE>
__global__ __launch_bounds__(256) void gemm_tn(
    const u16* __restrict__ A, long sAb, int pa, int ma,
    const u16* __restrict__ Bm, long sBb, int pb, int mb, int ktot,
    u16* __restrict__ outb, long sOb, u16* __restrict__ S,
    u32* __restrict__ Mru, u32* __restrict__ Mcu) {
  const int bz = blockIdx.z;
  const u16* Ab = A + (size_t)bz * sAb;
  const u16* Bb = Bm + (size_t)bz * sBb;
  int m0, n0;
  if (MODE == 0) {
    m0 = blockIdx.x * 128;
    n0 = blockIdx.y * 128;
  } else {
    const int bidl = blockIdx.x + (int)gridDim.x * blockIdx.y;  // 0..1023
    const int xcd = bidl & 7, idx = bidl >> 3;
    const int mt = (xcd & 3) * 8 + (idx & 7);
    const int nt = (xcd >> 2) * 16 + (idx >> 3);
    m0 = mt * 128;
    n0 = nt * 128;
  }
  const int tid = threadIdx.x;
  const int wave = tid >> 6;
  const int lane = tid & 63;
  const int q = lane >> 4;
  const int l = lane & 15;
  const int l7 = l & 7;
  const int wm = (wave >> 1) * 64;
  const int wn = (wave & 1) * 64;
  const int sr = lane >> 3;  // row-in-group 0..7
  const int sp = lane & 7;   // LDS chunk position 0..7
  const int sg = sp ^ sr;    // global chunk index (swizzle)

  __shared__ alignas(16) u16 sA[128 * 64];
  __shared__ alignas(16) u16 sB[128 * 64];

  v4f zero = {0.f, 0.f, 0.f, 0.f};
  v4f acc[4][4];
#pragma unroll
  for (int i = 0; i < 4; i++)
#pragma unroll
    for (int j = 0; j < 4; j++) acc[i][j] = zero;

  for (int k0 = 0; k0 < ktot; k0 += 64) {
    const int kA = k0 & ma;
    const int kB = k0 & mb;
    __syncthreads();
#pragma unroll
    for (int ii = 0; ii < 4; ii++) {
      int r = wave * 32 + ii * 8 + sr;
      async16(Ab + (size_t)(m0 + r) * pa + kA + sg * 8,
              &sA[r * 64 + sp * 8]);
    }
#pragma unroll
    for (int ii = 0; ii < 4; ii++) {
      int r = wave * 32 + ii * 8 + sr;
      async16(Bb + (size_t)(n0 + r) * pb + kB + sg * 8,
              &sB[r * 64 + sp * 8]);
    }
    __syncthreads();
#pragma unroll
    for (int s = 0; s < 2; s++) {
      const int pa8 = (s * 4 + q) ^ l7;
      v8h af[4], bfr[4];
#pragma unroll
      for (int i = 0; i < 4; i++)
        af[i] = *(const v8h*)&sA[(wm + i * 16 + l) * 64 + pa8 * 8];
#pragma unroll
      for (int j = 0; j < 4; j++)
        bfr[j] = *(const v8h*)&sB[(wn + j * 16 + l) * 64 + pa8 * 8];
#pragma unroll
      for (int i = 0; i < 4; i++)
#pragma unroll
        for (int j = 0; j < 4; j++)
          acc[i][j] = __builtin_amdgcn_mfma_f32_16x16x32_f16(af[i], bfr[j],
                                                             acc[i][j], 0, 0, 0);
    }
  }

  if (MODE == 0) {
    u16* ob = outb + (size_t)bz * sOb;
#pragma unroll
    for (int i = 0; i < 4; i++)
#pragma unroll
      for (int j = 0; j < 4; j++)
#pragma unroll
        for (int r = 0; r < 4; r++) {
          int row = m0 + wm + i * 16 + q * 4 + r;
          int col = n0 + wn + j * 16 + l;
          ob[(size_t)row * 256 + col] = f2h(acc[i][j][r]);
        }
  } else {
    u16* Sb = S + (size_t)bz * ((size_t)NNN * NNN);
    u32* Mrb = Mru + bz * 4096;
    u32* Mcb = Mcu + bz * 4096;
#pragma unroll
    for (int i = 0; i < 4; i++)
#pragma unroll
      for (int j = 0; j < 4; j++)
#pragma unroll
        for (int r = 0; r < 4; r++) {
          int row = m0 + wm + i * 16 + q * 4 + r;  // S row n
          int col = n0 + wn + j * 16 + l;          // S col m
          Sb[(size_t)row * NNN + col] = f2h(acc[i][j][r]);
        }
    // --- row max (over this block's 128 cols) ---
    float rm[4][4];
#pragma unroll
    for (int i = 0; i < 4; i++)
#pragma unroll
      for (int r = 0; r < 4; r++)
        rm[i][r] = fmaxf(fmaxf(acc[i][0][r], acc[i][1][r]),
                         fmaxf(acc[i][2][r], acc[i][3][r]));
#pragma unroll
    for (int off = 1; off < 16; off <<= 1)
#pragma unroll
      for (int i = 0; i < 4; i++)
#pragma unroll
        for (int r = 0; r < 4; r++)
          rm[i][r] = fmaxf(rm[i][r], __shfl_xor(rm[i][r], off));
    if (l == 0) {
#pragma unroll
      for (int i = 0; i < 4; i++)
#pragma unroll
        for (int r = 0; r < 4; r++)
          atomicMax(&Mrb[m0 + wm + i * 16 + q * 4 + r], encf(rm[i][r]));
    }
    // --- col max (over this block's 128 rows) ---
    float cm[4];
#pragma unroll
    for (int j = 0; j < 4; j++) {
      float v = -3e38f;
#pragma unroll
      for (int i = 0; i < 4; i++)
#pragma unroll
        for (int r = 0; r < 4; r++) v = fmaxf(v, acc[i][j][r]);
      cm[j] = v;
    }
#pragma unroll
    for (int off = 16; off < 64; off <<= 1)
#pragma unroll
      for (int j = 0; j < 4; j++) cm[j] = fmaxf(cm[j], __shfl_xor(cm[j], off));
    if (q == 0) {
#pragma unroll
      for (int j = 0; j < 4; j++)
        atomicMax(&Mcb[n0 + wn + j * 16 + l], encf(cm[j]));
    }
  }
}

// ---- FULL-K PV, x-split x2: block owns ALL 256 c-rows x 32 x-cols.
// Grid 1024 = 4 batches x 2 sides x 128 x-strips = exactly 4 blocks/CU.
// Unlike R14's c-split (duplicated exp/pack VALU -> regressed), x-split
// duplicates NOTHING on the VALU or HBM path: S is partitioned by x
// (exp total unchanged), MFMA total unchanged; only the V staging is
// issued 2x (from the L2-resident 2 MB slab, ~2-3 TB/s per XCD < the
// ~4.3 TB/s L2 ceiling). acc[4][2] (~80 VGPR), LDS 38 KB -> 4 resident.
__global__ __launch_bounds__(256) void pv_part(
    const u16* __restrict__ aV, const u16* __restrict__ bV,
    const u16* __restrict__ S, const u32* __restrict__ Mru,
    const u32* __restrict__ Mcu, float* __restrict__ outA,
    float* __restrict__ outB) {
  const int lin = blockIdx.x + 64 * (blockIdx.y + 4 * blockIdx.z);  // 0..1023
  const int xcd = lin & 7;
  const int which = xcd & 1;
  const int bp = xcd >> 1;         // batch 0..3
  const int x0 = (lin >> 3) * 32;  // 128 x-strips of 32
  const u16* Av = (which ? bV : aV) + (size_t)bp * (CC * NNN);
  const u32* Mst = (which ? Mru : Mcu) + bp * 4096;
  const u16* Sg = S + (size_t)bp * ((size_t)NNN * NNN);
  float* Outp = (which ? outB : outA) + (size_t)bp * CC * NNN;

  const int tid = threadIdx.x;
  const int wave = tid >> 6, lane = tid & 63, q = lane >> 4, l = lane & 15;
  const int l7 = l & 7;
  const int sr = lane >> 3, sp = lane & 7, sg = sp ^ sr;
  // which=1 S-read coords: 32 x-rows x 8 chunks of 8 k (one v8h each)
  const int xl = tid >> 3, ch = tid & 7;
  // which=0 S-read coords: 32 x-cols x 8 groups of 8 k-rows
  const int xs = tid & 31, kq = (tid >> 5) * 8;
  const int xr = which ? xl : xs;
  const int g0 = which ? ch : (tid >> 5);

  __shared__ alignas(16) u16 sA[256 * 64];
  __shared__ alignas(16) u16 sB[32 * 64];
  __shared__ float lsh[256];
  __shared__ float Lx[32];

  v4f zero = {0.f, 0.f, 0.f, 0.f};
  v4f acc[4][2];
#pragma unroll
  for (int i = 0; i < 4; i++)
#pragma unroll
    for (int j = 0; j < 2; j++) acc[i][j] = zero;

  const float mx = decf(Mst[x0 + xr]);
  float lsum = 0.f;

  for (int k0 = 0; k0 < NNN; k0 += 64) {
    __syncthreads();
#pragma unroll
    for (int ii = 0; ii < 8; ii++) {
      int r = wave * 64 + ii * 8 + sr;
      async16(Av + (size_t)r * NNN + k0 + sg * 8, &sA[r * 64 + sp * 8]);
    }
    {
      float e[8];
      if (which) {
        const u16* gp = Sg + (size_t)(x0 + xl) * NNN + k0 + ch * 8;
        v8h h0 = *(const v8h*)gp;
#pragma unroll
        for (int t = 0; t < 8; t++) e[t] = __expf((float)h0[t] - mx);
      } else {
        const u16* gp = Sg + (size_t)(k0 + kq) * NNN + x0 + xs;
#pragma unroll
        for (int t = 0; t < 8; t++)
          e[t] = __expf((float)(*(const f16*)&gp[(size_t)t * NNN]) - mx);
      }
#pragma unroll
      for (int t = 0; t < 8; t++) lsum += e[t];
      v8h pk;
#pragma unroll
      for (int t = 0; t < 8; t++) pk[t] = (f16)e[t];
      *(v8h*)&sB[xr * 64 + (g0 ^ (xr & 7)) * 8] = pk;
    }
    __syncthreads();
#pragma unroll
    for (int s = 0; s < 2; s++) {
      const int pa8 = (s * 4 + q) ^ l7;
      v8h af[4], bfr[2];
#pragma unroll
      for (int i = 0; i < 4; i++)
        af[i] = *(const v8h*)&sA[(wave * 64 + i * 16 + l) * 64 + pa8 * 8];
#pragma unroll
      for (int j = 0; j < 2; j++)
        bfr[j] = *(const v8h*)&sB[(j * 16 + l) * 64 + pa8 * 8];
#pragma unroll
      for (int i = 0; i < 4; i++)
#pragma unroll
        for (int j = 0; j < 2; j++)
          acc[i][j] = __builtin_amdgcn_mfma_f32_16x16x32_f16(af[i], bfr[j],
                                                             acc[i][j], 0, 0, 0);
    }
  }

  // L reduction: 8 threads contribute per x -> Lx = 1/L
  __syncthreads();
  lsh[tid] = lsum;
  __syncthreads();
  if (tid < 32) {
    float t = 0.f;
#pragma unroll
    for (int u = 0; u < 8; u++)
      t += which ? lsh[tid * 8 + u] : lsh[tid + 32 * u];
    Lx[tid] = 1.0f / t;
  }
  __syncthreads();

#pragma unroll
  for (int i = 0; i < 4; i++)
#pragma unroll
    for (int j = 0; j < 2; j++) {
      const float rl = Lx[j * 16 + l];
#pragma unroll
      for (int r = 0; r < 4; r++) {
        int c = wave * 64 + i * 16 + q * 4 + r;
        Outp[(size_t)c * NNN + x0 + j * 16 + l] = acc[i][j][r] * rl;
      }
    }
}

extern "C" void kernel_launch(void* const* d_in, const int* in_sizes, int n_in,
                              void* d_out, int out_size, void* d_ws,
                              size_t ws_size, hipStream_t stream) {
  const float* a = (const float*)d_in[0];
  const float* b = (const float*)d_in[1];
  const float* W = (const float*)d_in[2];
  float* out = (float*)d_out;

  char* ws = (char*)d_ws;
  u16* Ws = (u16*)(ws);                     // 131072 (256KB rsvd)
  u16* aT = (u16*)(ws + 262144);            // 8388608
  u16* bT = (u16*)(ws + 8650752);           // 8388608
  u16* aCb = (u16*)(ws + 17039360);         // 8388608
  u16* bCb = (u16*)(ws + 25427968);         // 8388608
  u16* ats = (u16*)(ws + 33816576);         // 8388608 (16MB rsvd)
  u32* Mru = (u32*)(ws + 50593792);         // [4][4096] u32 = 65536
  u32* Mcu = (u32*)(ws + 50659328);         // 65536
  u16* Sbuf = (u16*)(ws + 51249152);        // 4 batches fp16 = 134217728
                                            // ends ~185.5 MB

  wsplit<<<dim3(256), 256, 0, stream>>>(W, Ws);
  tsplit<<<dim3(64, 4, 8), 256, 0, stream>>>(a, b, aT, bT, aCb, bCb);
  // a~[n][d] = sum_c aT[n][c] * W[d][c], K=256, out single fp16 pitch 256
  gemm_tn<0><<<dim3(32, 2, 4), 256, 0, stream>>>(
      aT, (long)NNN * 256, 256, 255, Ws, 0, 256, 255, 256,
      ats, (long)NNN * 256, nullptr, nullptr, nullptr);
  hipMemsetAsync(Mru, 0, 131072, stream);  // all 4 batches' Mru+Mcu

  // S[n][m] for all 4 batches in one launch (z = batch)
  gemm_tn<1><<<dim3(32, 32, 4), 256, 0, stream>>>(
      ats, (long)NNN * 256, 256, 255, bT, (long)NNN * 256, 256, 255, 256,
      nullptr, 0, Sbuf, Mru, Mcu);
  // full-K PV + softmax-divide, x-split x2, writes out directly
  pv_part<<<dim3(64, 4, 4), 256, 0, stream>>>(
      aCb, bCb, Sbuf, Mru, Mcu, out, out + 4194304);
}

// Round 17
// 287.921 us; speedup vs baseline: 1.1017x; 1.1017x over previous
//
#include <hip/hip_runtime.h>
#include <stdint.h>

typedef unsigned short u16;
typedef unsigned int u32;
typedef _Float16 f16;
typedef float v4f __attribute__((ext_vector_type(4)));
typedef f16 v8h __attribute__((ext_vector_type(8)));

#define CC 256
#define NNN 4096

__device__ __forceinline__ u16 f2h(float f) {
  union { f16 h; u16 u; } c; c.h = (f16)f; return c.u;
}
__device__ __forceinline__ float h2f(u16 u) {
  union { f16 h; u16 u; } c; c.u = u; return (float)c.h;
}
// monotone float<->uint encoding for atomicMax on fp32
__device__ __forceinline__ u32 encf(float f) {
  u32 u = __float_as_uint(f);
  return (u >> 31) ? ~u : (u | 0x80000000u);
}
__device__ __forceinline__ float decf(u32 u) {
  return (u >> 31) ? __uint_as_float(u & 0x7fffffffu) : __uint_as_float(~u);
}
__device__ __forceinline__ void async16(const void* g, void* l) {
  __builtin_amdgcn_global_load_lds(
      (const __attribute__((address_space(1))) uint32_t*)g,
      (__attribute__((address_space(3))) uint32_t*)l, 16, 0, 0);
}

// ---- W [256][256] fp32 -> Ws [256][256] single fp16, K(c)-fast ----
__global__ __launch_bounds__(256) void wsplit(const float* __restrict__ W,
                                              u16* __restrict__ Ws) {
  const int d = blockIdx.x, c = threadIdx.x;
  Ws[d * 256 + c] = f2h(W[d * 256 + c]);
}

// ---- both inputs, all batches: in [C][N] fp32 -> T [N][256] fp16
// (transposed) and Cb [C][N] fp16 copy. z = batch(0..3) | which<<2. ----
__global__ __launch_bounds__(256) void tsplit(
    const float* __restrict__ asrc, const float* __restrict__ bsrc,
    u16* __restrict__ aT, u16* __restrict__ bT,
    u16* __restrict__ aCb, u16* __restrict__ bCb) {
  __shared__ u16 th[64][65];
  const int bz = blockIdx.z;
  const int bb = bz & 3;
  const int wh = bz >> 2;
  const int n0 = blockIdx.x * 64;
  const int c0 = blockIdx.y * 64;
  const int tx = threadIdx.x & 63;
  const int ty = threadIdx.x >> 6;  // 0..3
  const float* ib = (wh ? bsrc : asrc) + (size_t)bb * CC * NNN;
  u16* Tb = (wh ? bT : aT) + (size_t)bb * NNN * 256;
  u16* Cbb = (wh ? bCb : aCb) + (size_t)bb * CC * NNN;
#pragma unroll
  for (int k = 0; k < 16; k++) {
    int r = ty + k * 4;
    float v = ib[(size_t)(c0 + r) * NNN + n0 + tx];
    u16 h = f2h(v);
    th[r][tx] = h;
    Cbb[(size_t)(c0 + r) * NNN + n0 + tx] = h;
  }
  __syncthreads();
#pragma unroll
  for (int k = 0; k < 16; k++) {
    int r = ty + k * 4;
    Tb[(size_t)(n0 + r) * 256 + c0 + tx] = th[tx][r];
  }
}

// ---- TN GEMM over fp16, K=256. BK=64, XOR-swizzled LDS.
// MODE 0: out = a~ single fp16, pitch 256.
// MODE 1: out = S fp16 + row/col max atomics; per-z batch slabs;
//         tiles XCD-clustered in xy.
template <int MODE>
__global__ __launch_bounds__(256) void gemm_tn(
    const u16* __restrict__ A, long sAb, int pa, int ma,
    const u16* __restrict__ Bm, long sBb, int pb, int mb, int ktot,
    u16* __restrict__ outb, long sOb, u16* __restrict__ S,
    u32* __restrict__ Mru, u32* __restrict__ Mcu) {
  const int bz = blockIdx.z;
  const u16* Ab = A + (size_t)bz * sAb;
  const u16* Bb = Bm + (size_t)bz * sBb;
  int m0, n0;
  if (MODE == 0) {
    m0 = blockIdx.x * 128;
    n0 = blockIdx.y * 128;
  } else {
    const int bidl = blockIdx.x + (int)gridDim.x * blockIdx.y;  // 0..1023
    const int xcd = bidl & 7, idx = bidl >> 3;
    const int mt = (xcd & 3) * 8 + (idx & 7);
    const int nt = (xcd >> 2) * 16 + (idx >> 3);
    m0 = mt * 128;
    n0 = nt * 128;
  }
  const int tid = threadIdx.x;
  const int wave = tid >> 6;
  const int lane = tid & 63;
  const int q = lane >> 4;
  const int l = lane & 15;
  const int l7 = l & 7;
  const int wm = (wave >> 1) * 64;
  const int wn = (wave & 1) * 64;
  const int sr = lane >> 3;  // row-in-group 0..7
  const int sp = lane & 7;   // LDS chunk position 0..7
  const int sg = sp ^ sr;    // global chunk index (swizzle)

  __shared__ alignas(16) u16 sA[128 * 64];
  __shared__ alignas(16) u16 sB[128 * 64];

  v4f zero = {0.f, 0.f, 0.f, 0.f};
  v4f acc[4][4];
#pragma unroll
  for (int i = 0; i < 4; i++)
#pragma unroll
    for (int j = 0; j < 4; j++) acc[i][j] = zero;

  for (int k0 = 0; k0 < ktot; k0 += 64) {
    const int kA = k0 & ma;
    const int kB = k0 & mb;
    __syncthreads();
#pragma unroll
    for (int ii = 0; ii < 4; ii++) {
      int r = wave * 32 + ii * 8 + sr;
      async16(Ab + (size_t)(m0 + r) * pa + kA + sg * 8,
              &sA[r * 64 + sp * 8]);
    }
#pragma unroll
    for (int ii = 0; ii < 4; ii++) {
      int r = wave * 32 + ii * 8 + sr;
      async16(Bb + (size_t)(n0 + r) * pb + kB + sg * 8,
              &sB[r * 64 + sp * 8]);
    }
    __syncthreads();
#pragma unroll
    for (int s = 0; s < 2; s++) {
      const int pa8 = (s * 4 + q) ^ l7;
      v8h af[4], bfr[4];
#pragma unroll
      for (int i = 0; i < 4; i++)
        af[i] = *(const v8h*)&sA[(wm + i * 16 + l) * 64 + pa8 * 8];
#pragma unroll
      for (int j = 0; j < 4; j++)
        bfr[j] = *(const v8h*)&sB[(wn + j * 16 + l) * 64 + pa8 * 8];
#pragma unroll
      for (int i = 0; i < 4; i++)
#pragma unroll
        for (int j = 0; j < 4; j++)
          acc[i][j] = __builtin_amdgcn_mfma_f32_16x16x32_f16(af[i], bfr[j],
                                                             acc[i][j], 0, 0, 0);
    }
  }

  if (MODE == 0) {
    u16* ob = outb + (size_t)bz * sOb;
#pragma unroll
    for (int i = 0; i < 4; i++)
#pragma unroll
      for (int j = 0; j < 4; j++)
#pragma unroll
        for (int r = 0; r < 4; r++) {
          int row = m0 + wm + i * 16 + q * 4 + r;
          int col = n0 + wn + j * 16 + l;
          ob[(size_t)row * 256 + col] = f2h(acc[i][j][r]);
        }
  } else {
    u16* Sb = S + (size_t)bz * ((size_t)NNN * NNN);
    u32* Mrb = Mru + bz * 4096;
    u32* Mcb = Mcu + bz * 4096;
#pragma unroll
    for (int i = 0; i < 4; i++)
#pragma unroll
      for (int j = 0; j < 4; j++)
#pragma unroll
        for (int r = 0; r < 4; r++) {
          int row = m0 + wm + i * 16 + q * 4 + r;  // S row n
          int col = n0 + wn + j * 16 + l;          // S col m
          Sb[(size_t)row * NNN + col] = f2h(acc[i][j][r]);
        }
    // --- row max (over this block's 128 cols) ---
    float rm[4][4];
#pragma unroll
    for (int i = 0; i < 4; i++)
#pragma unroll
      for (int r = 0; r < 4; r++)
        rm[i][r] = fmaxf(fmaxf(acc[i][0][r], acc[i][1][r]),
                         fmaxf(acc[i][2][r], acc[i][3][r]));
#pragma unroll
    for (int off = 1; off < 16; off <<= 1)
#pragma unroll
      for (int i = 0; i < 4; i++)
#pragma unroll
        for (int r = 0; r < 4; r++)
          rm[i][r] = fmaxf(rm[i][r], __shfl_xor(rm[i][r], off));
    if (l == 0) {
#pragma unroll
      for (int i = 0; i < 4; i++)
#pragma unroll
        for (int r = 0; r < 4; r++)
          atomicMax(&Mrb[m0 + wm + i * 16 + q * 4 + r], encf(rm[i][r]));
    }
    // --- col max (over this block's 128 rows) ---
    float cm[4];
#pragma unroll
    for (int j = 0; j < 4; j++) {
      float v = -3e38f;
#pragma unroll
      for (int i = 0; i < 4; i++)
#pragma unroll
        for (int r = 0; r < 4; r++) v = fmaxf(v, acc[i][j][r]);
      cm[j] = v;
    }
#pragma unroll
    for (int off = 16; off < 64; off <<= 1)
#pragma unroll
      for (int j = 0; j < 4; j++) cm[j] = fmaxf(cm[j], __shfl_xor(cm[j], off));
    if (q == 0) {
#pragma unroll
      for (int j = 0; j < 4; j++)
        atomicMax(&Mcb[n0 + wn + j * 16 + l], encf(cm[j]));
    }
  }
}

// ---- FULL-K PV, all 4 batches, no k-split, fused divide (R13 state —
// the verified optimum across 8 attempted restructures: c-split dup'd
// exp VALU (R14 +13us), x-split dup'd V staging (R16 +33us), k-split
// dup'd Ppart traffic (R12 +30us), dbuf/reg-V/prefetch all regressed).
// 512 blocks = 4 batches x 2 sides x 64 x-tiles = exactly 2 blocks/CU,
// zero tail. Each XCD owns one (batch,which): 2 MB V slab L2-resident,
// 32 MB S slab streams once. L complete at loop end -> multiply by 1/L
// and write fp32 out directly.
__global__ __launch_bounds__(256) void pv_part(
    const u16* __restrict__ aV, const u16* __restrict__ bV,
    const u16* __restrict__ S, const u32* __restrict__ Mru,
    const u32* __restrict__ Mcu, float* __restrict__ outA,
    float* __restrict__ outB) {
  const int lin = blockIdx.x + 64 * (blockIdx.y + 2 * blockIdx.z);  // 0..511
  const int xcd = lin & 7;
  const int which = xcd & 1;
  const int bp = xcd >> 1;         // batch 0..3
  const int x0 = (lin >> 3) * 64;  // 64 x-tiles
  const u16* Av = (which ? bV : aV) + (size_t)bp * (CC * NNN);
  const u32* Mst = (which ? Mru : Mcu) + bp * 4096;
  const u16* Sg = S + (size_t)bp * ((size_t)NNN * NNN);
  float* Outp = (which ? outB : outA) + (size_t)bp * CC * NNN;

  const int tid = threadIdx.x;
  const int wave = tid >> 6, lane = tid & 63, q = lane >> 4, l = lane & 15;
  const int l7 = l & 7;
  const int sr = lane >> 3, sp = lane & 7, sg = sp ^ sr;
  // which=1 S-read coords: 64 x-rows x 4 chunks of 16 k
  const int xl = tid >> 2, ch = tid & 3;
  // which=0 S-read coords: 64 x-cols x 4 groups of 16 k-rows
  const int xs = tid & 63, kq = (tid >> 6) * 16;

  __shared__ alignas(16) u16 sA[256 * 64];
  __shared__ alignas(16) u16 sB[64 * 64];
  __shared__ float lsh[256];
  __shared__ float Lx[64];

  v4f zero = {0.f, 0.f, 0.f, 0.f};
  v4f acc[4][4];
#pragma unroll
  for (int i = 0; i < 4; i++)
#pragma unroll
    for (int j = 0; j < 4; j++) acc[i][j] = zero;

  const float mx = decf(Mst[x0 + (which ? xl : xs)]);
  float lsum = 0.f;

  for (int k0 = 0; k0 < NNN; k0 += 64) {
    __syncthreads();
#pragma unroll
    for (int ii = 0; ii < 8; ii++) {
      int r = wave * 64 + ii * 8 + sr;
      async16(Av + (size_t)r * NNN + k0 + sg * 8, &sA[r * 64 + sp * 8]);
    }
    if (which) {
      const u16* gp = Sg + (size_t)(x0 + xl) * NNN + k0 + ch * 16;
      v8h h0 = *(const v8h*)gp;
      v8h h1 = *(const v8h*)(gp + 8);
      float e[16];
#pragma unroll
      for (int t = 0; t < 8; t++) {
        e[t] = __expf((float)h0[t] - mx);
        e[t + 8] = __expf((float)h1[t] - mx);
      }
#pragma unroll
      for (int t = 0; t < 16; t++) lsum += e[t];
      v8h pk0, pk1;
#pragma unroll
      for (int t = 0; t < 8; t++) {
        pk0[t] = (f16)e[t];
        pk1[t] = (f16)e[t + 8];
      }
      const int g0 = ch * 2;
      *(v8h*)&sB[xl * 64 + (g0 ^ (xl & 7)) * 8] = pk0;
      *(v8h*)&sB[xl * 64 + ((g0 + 1) ^ (xl & 7)) * 8] = pk1;
    } else {
      const u16* gp = Sg + (size_t)(k0 + kq) * NNN + x0 + xs;
      float e[16];
#pragma unroll
      for (int t = 0; t < 16; t++)
        e[t] = __expf((float)(*(const f16*)&gp[(size_t)t * NNN]) - mx);
#pragma unroll
      for (int t = 0; t < 16; t++) lsum += e[t];
      v8h pk0, pk1;
#pragma unroll
      for (int t = 0; t < 8; t++) {
        pk0[t] = (f16)e[t];
        pk1[t] = (f16)e[t + 8];
      }
      const int g0 = (tid >> 6) * 2;
      *(v8h*)&sB[xs * 64 + (g0 ^ (xs & 7)) * 8] = pk0;
      *(v8h*)&sB[xs * 64 + ((g0 + 1) ^ (xs & 7)) * 8] = pk1;
    }
    __syncthreads();
#pragma unroll
    for (int s = 0; s < 2; s++) {
      const int pa8 = (s * 4 + q) ^ l7;
      v8h af[4], bfr[4];
#pragma unroll
      for (int i = 0; i < 4; i++)
        af[i] = *(const v8h*)&sA[(wave * 64 + i * 16 + l) * 64 + pa8 * 8];
#pragma unroll
      for (int j = 0; j < 4; j++)
        bfr[j] = *(const v8h*)&sB[(j * 16 + l) * 64 + pa8 * 8];
#pragma unroll
      for (int i = 0; i < 4; i++)
#pragma unroll
        for (int j = 0; j < 4; j++)
          acc[i][j] = __builtin_amdgcn_mfma_f32_16x16x32_f16(af[i], bfr[j],
                                                             acc[i][j], 0, 0, 0);
    }
  }

  // L reduction: 4 threads contribute per x -> Lx = 1/L
  __syncthreads();
  lsh[tid] = lsum;
  __syncthreads();
  if (tid < 64) {
    float t;
    if (which)
      t = (lsh[tid * 4] + lsh[tid * 4 + 1]) + (lsh[tid * 4 + 2] + lsh[tid * 4 + 3]);
    else
      t = (lsh[tid] + lsh[tid + 64]) + (lsh[tid + 128] + lsh[tid + 192]);
    Lx[tid] = 1.0f / t;
  }
  __syncthreads();

#pragma unroll
  for (int i = 0; i < 4; i++)
#pragma unroll
    for (int j = 0; j < 4; j++) {
      const float rl = Lx[j * 16 + l];
#pragma unroll
      for (int r = 0; r < 4; r++) {
        int c = wave * 64 + i * 16 + q * 4 + r;
        Outp[(size_t)c * NNN + x0 + j * 16 + l] = acc[i][j][r] * rl;
      }
    }
}

extern "C" void kernel_launch(void* const* d_in, const int* in_sizes, int n_in,
                              void* d_out, int out_size, void* d_ws,
                              size_t ws_size, hipStream_t stream) {
  const float* a = (const float*)d_in[0];
  const float* b = (const float*)d_in[1];
  const float* W = (const float*)d_in[2];
  float* out = (float*)d_out;

  char* ws = (char*)d_ws;
  u16* Ws = (u16*)(ws);                     // 131072 (256KB rsvd)
  u16* aT = (u16*)(ws + 262144);            // 8388608
  u16* bT = (u16*)(ws + 8650752);           // 8388608
  u16* aCb = (u16*)(ws + 17039360);         // 8388608
  u16* bCb = (u16*)(ws + 25427968);         // 8388608
  u16* ats = (u16*)(ws + 33816576);         // 8388608 (16MB rsvd)
  u32* Mru = (u32*)(ws + 50593792);         // [4][4096] u32 = 65536
  u32* Mcu = (u32*)(ws + 50659328);         // 65536
  u16* Sbuf = (u16*)(ws + 51249152);        // 4 batches fp16 = 134217728
                                            // ends ~185.5 MB

  wsplit<<<dim3(256), 256, 0, stream>>>(W, Ws);
  tsplit<<<dim3(64, 4, 8), 256, 0, stream>>>(a, b, aT, bT, aCb, bCb);
  // a~[n][d] = sum_c aT[n][c] * W[d][c], K=256, out single fp16 pitch 256
  gemm_tn<0><<<dim3(32, 2, 4), 256, 0, stream>>>(
      aT, (long)NNN * 256, 256, 255, Ws, 0, 256, 255, 256,
      ats, (long)NNN * 256, nullptr, nullptr, nullptr);
  hipMemsetAsync(Mru, 0, 131072, stream);  // all 4 batches' Mru+Mcu

  // S[n][m] for all 4 batches in one launch (z = batch)
  gemm_tn<1><<<dim3(32, 32, 4), 256, 0, stream>>>(
      ats, (long)NNN * 256, 256, 255, bT, (long)NNN * 256, 256, 255, 256,
      nullptr, 0, Sbuf, Mru, Mcu);
  // full-K PV + softmax-divide, writes out directly
  pv_part<<<dim3(64, 2, 4), 256, 0, stream>>>(
      aCb, bCb, Sbuf, Mru, Mcu, out, out + 4194304);
}

// Round 18
// 276.223 us; speedup vs baseline: 1.1483x; 1.0424x over previous
//
#include <hip/hip_runtime.h>
#include <stdint.h>

typedef unsigned short u16;
typedef unsigned int u32;
typedef _Float16 f16;
typedef float v4f __attribute__((ext_vector_type(4)));
typedef f16 v8h __attribute__((ext_vector_type(8)));

#define CC 256
#define NNN 4096

__device__ __forceinline__ u16 f2h(float f) {
  union { f16 h; u16 u; } c; c.h = (f16)f; return c.u;
}
__device__ __forceinline__ float h2f(u16 u) {
  union { f16 h; u16 u; } c; c.u = u; return (float)c.h;
}
// monotone float<->uint encoding for atomicMax on fp32
__device__ __forceinline__ u32 encf(float f) {
  u32 u = __float_as_uint(f);
  return (u >> 31) ? ~u : (u | 0x80000000u);
}
__device__ __forceinline__ float decf(u32 u) {
  return (u >> 31) ? __uint_as_float(u & 0x7fffffffu) : __uint_as_float(~u);
}
__device__ __forceinline__ void async16(const void* g, void* l) {
  __builtin_amdgcn_global_load_lds(
      (const __attribute__((address_space(1))) uint32_t*)g,
      (__attribute__((address_space(3))) uint32_t*)l, 16, 0, 0);
}

// ---- W [256][256] fp32 -> Ws [256][256] single fp16, K(c)-fast ----
__global__ __launch_bounds__(256) void wsplit(const float* __restrict__ W,
                                              u16* __restrict__ Ws) {
  const int d = blockIdx.x, c = threadIdx.x;
  Ws[d * 256 + c] = f2h(W[d * 256 + c]);
}

// ---- both inputs, all batches: in [C][N] fp32 -> T [N][256] fp16
// (transposed) and Cb [C][N] fp16 copy. z = batch(0..3) | which<<2. ----
__global__ __launch_bounds__(256) void tsplit(
    const float* __restrict__ asrc, const float* __restrict__ bsrc,
    u16* __restrict__ aT, u16* __restrict__ bT,
    u16* __restrict__ aCb, u16* __restrict__ bCb) {
  __shared__ u16 th[64][65];
  const int bz = blockIdx.z;
  const int bb = bz & 3;
  const int wh = bz >> 2;
  const int n0 = blockIdx.x * 64;
  const int c0 = blockIdx.y * 64;
  const int tx = threadIdx.x & 63;
  const int ty = threadIdx.x >> 6;  // 0..3
  const float* ib = (wh ? bsrc : asrc) + (size_t)bb * CC * NNN;
  u16* Tb = (wh ? bT : aT) + (size_t)bb * NNN * 256;
  u16* Cbb = (wh ? bCb : aCb) + (size_t)bb * CC * NNN;
#pragma unroll
  for (int k = 0; k < 16; k++) {
    int r = ty + k * 4;
    float v = ib[(size_t)(c0 + r) * NNN + n0 + tx];
    u16 h = f2h(v);
    th[r][tx] = h;
    Cbb[(size_t)(c0 + r) * NNN + n0 + tx] = h;
  }
  __syncthreads();
#pragma unroll
  for (int k = 0; k < 16; k++) {
    int r = ty + k * 4;
    Tb[(size_t)(n0 + r) * 256 + c0 + tx] = th[tx][r];
  }
}

// ---- TN GEMM over fp16, K=256. BK=64, XOR-swizzled LDS.
// MODE 0: out = a~ single fp16, pitch 256.
// MODE 1: out = S fp16 + row/col max atomics; per-z batch slabs;
//         tiles XCD-clustered in xy.
template <int MODE>
__global__ __launch_bounds__(256) void gemm_tn(
    const u16* __restrict__ A, long sAb, int pa, int ma,
    const u16* __restrict__ Bm, long sBb, int pb, int mb, int ktot,
    u16* __restrict__ outb, long sOb, u16* __restrict__ S,
    u32* __restrict__ Mru, u32* __restrict__ Mcu) {
  const int bz = blockIdx.z;
  const u16* Ab = A + (size_t)bz * sAb;
  const u16* Bb = Bm + (size_t)bz * sBb;
  int m0, n0;
  if (MODE == 0) {
    m0 = blockIdx.x * 128;
    n0 = blockIdx.y * 128;
  } else {
    const int bidl = blockIdx.x + (int)gridDim.x * blockIdx.y;  // 0..1023
    const int xcd = bidl & 7, idx = bidl >> 3;
    const int mt = (xcd & 3) * 8 + (idx & 7);
    const int nt = (xcd >> 2) * 16 + (idx >> 3);
    m0 = mt * 128;
    n0 = nt * 128;
  }
  const int tid = threadIdx.x;
  const int wave = tid >> 6;
  const int lane = tid & 63;
  const int q = lane >> 4;
  const int l = lane & 15;
  const int l7 = l & 7;
  const int wm = (wave >> 1) * 64;
  const int wn = (wave & 1) * 64;
  const int sr = lane >> 3;  // row-in-group 0..7
  const int sp = lane & 7;   // LDS chunk position 0..7
  const int sg = sp ^ sr;    // global chunk index (swizzle)

  __shared__ alignas(16) u16 sA[128 * 64];
  __shared__ alignas(16) u16 sB[128 * 64];

  v4f zero = {0.f, 0.f, 0.f, 0.f};
  v4f acc[4][4];
#pragma unroll
  for (int i = 0; i < 4; i++)
#pragma unroll
    for (int j = 0; j < 4; j++) acc[i][j] = zero;

  for (int k0 = 0; k0 < ktot; k0 += 64) {
    const int kA = k0 & ma;
    const int kB = k0 & mb;
    __syncthreads();
#pragma unroll
    for (int ii = 0; ii < 4; ii++) {
      int r = wave * 32 + ii * 8 + sr;
      async16(Ab + (size_t)(m0 + r) * pa + kA + sg * 8,
              &sA[r * 64 + sp * 8]);
    }
#pragma unroll
    for (int ii = 0; ii < 4; ii++) {
      int r = wave * 32 + ii * 8 + sr;
      async16(Bb + (size_t)(n0 + r) * pb + kB + sg * 8,
              &sB[r * 64 + sp * 8]);
    }
    __syncthreads();
#pragma unroll
    for (int s = 0; s < 2; s++) {
      const int pa8 = (s * 4 + q) ^ l7;
      v8h af[4], bfr[4];
#pragma unroll
      for (int i = 0; i < 4; i++)
        af[i] = *(const v8h*)&sA[(wm + i * 16 + l) * 64 + pa8 * 8];
#pragma unroll
      for (int j = 0; j < 4; j++)
        bfr[j] = *(const v8h*)&sB[(wn + j * 16 + l) * 64 + pa8 * 8];
#pragma unroll
      for (int i = 0; i < 4; i++)
#pragma unroll
        for (int j = 0; j < 4; j++)
          acc[i][j] = __builtin_amdgcn_mfma_f32_16x16x32_f16(af[i], bfr[j],
                                                             acc[i][j], 0, 0, 0);
    }
  }

  if (MODE == 0) {
    u16* ob = outb + (size_t)bz * sOb;
#pragma unroll
    for (int i = 0; i < 4; i++)
#pragma unroll
      for (int j = 0; j < 4; j++)
#pragma unroll
        for (int r = 0; r < 4; r++) {
          int row = m0 + wm + i * 16 + q * 4 + r;
          int col = n0 + wn + j * 16 + l;
          ob[(size_t)row * 256 + col] = f2h(acc[i][j][r]);
        }
  } else {
    u16* Sb = S + (size_t)bz * ((size_t)NNN * NNN);
    u32* Mrb = Mru + bz * 4096;
    u32* Mcb = Mcu + bz * 4096;
#pragma unroll
    for (int i = 0; i < 4; i++)
#pragma unroll
      for (int j = 0; j < 4; j++)
#pragma unroll
        for (int r = 0; r < 4; r++) {
          int row = m0 + wm + i * 16 + q * 4 + r;  // S row n
          int col = n0 + wn + j * 16 + l;          // S col m
          Sb[(size_t)row * NNN + col] = f2h(acc[i][j][r]);
        }
    // --- row max (over this block's 128 cols) ---
    float rm[4][4];
#pragma unroll
    for (int i = 0; i < 4; i++)
#pragma unroll
      for (int r = 0; r < 4; r++)
        rm[i][r] = fmaxf(fmaxf(acc[i][0][r], acc[i][1][r]),
                         fmaxf(acc[i][2][r], acc[i][3][r]));
#pragma unroll
    for (int off = 1; off < 16; off <<= 1)
#pragma unroll
      for (int i = 0; i < 4; i++)
#pragma unroll
        for (int r = 0; r < 4; r++)
          rm[i][r] = fmaxf(rm[i][r], __shfl_xor(rm[i][r], off));
    if (l == 0) {
#pragma unroll
      for (int i = 0; i < 4; i++)
#pragma unroll
        for (int r = 0; r < 4; r++)
          atomicMax(&Mrb[m0 + wm + i * 16 + q * 4 + r], encf(rm[i][r]));
    }
    // --- col max (over this block's 128 rows) ---
    float cm[4];
#pragma unroll
    for (int j = 0; j < 4; j++) {
      float v = -3e38f;
#pragma unroll
      for (int i = 0; i < 4; i++)
#pragma unroll
        for (int r = 0; r < 4; r++) v = fmaxf(v, acc[i][j][r]);
      cm[j] = v;
    }
#pragma unroll
    for (int off = 16; off < 64; off <<= 1)
#pragma unroll
      for (int j = 0; j < 4; j++) cm[j] = fmaxf(cm[j], __shfl_xor(cm[j], off));
    if (q == 0) {
#pragma unroll
      for (int j = 0; j < 4; j++)
        atomicMax(&Mcb[n0 + wn + j * 16 + l], encf(cm[j]));
    }
  }
}

// ---- FULL-K PV (R13 geometry: 512 blocks, 2/CU, no split) with ONE
// isolated change: the S tile for step t+1 is staged into LDS via
// fire-and-forget async16 (dbuf sS, 2x8 KB) alongside V(t), drained at
// the SAME barrier V already needed -> zero added exposed latency; the
// exp/pack at step t reads sS[t&1] from LDS (~60cy) instead of global
// (~500-900cy), removing the S-wait from the inter-barrier serial path.
// Same XOR-swizzle as the V path (src chunk sg2 = sp2^(r&7)).
// LDS 58.5 KB -> still 2 blocks/CU.
__global__ __launch_bounds__(256) void pv_part(
    const u16* __restrict__ aV, const u16* __restrict__ bV,
    const u16* __restrict__ S, const u32* __restrict__ Mru,
    const u32* __restrict__ Mcu, float* __restrict__ outA,
    float* __restrict__ outB) {
  const int lin = blockIdx.x + 64 * (blockIdx.y + 2 * blockIdx.z);  // 0..511
  const int xcd = lin & 7;
  const int which = xcd & 1;
  const int bp = xcd >> 1;         // batch 0..3
  const int x0 = (lin >> 3) * 64;  // 64 x-tiles
  const u16* Av = (which ? bV : aV) + (size_t)bp * (CC * NNN);
  const u32* Mst = (which ? Mru : Mcu) + bp * 4096;
  const u16* Sg = S + (size_t)bp * ((size_t)NNN * NNN);
  float* Outp = (which ? outB : outA) + (size_t)bp * CC * NNN;

  const int tid = threadIdx.x;
  const int wave = tid >> 6, lane = tid & 63, q = lane >> 4, l = lane & 15;
  const int l7 = l & 7;
  const int sr = lane >> 3, sp = lane & 7, sg = sp ^ sr;
  // S-tile staging coords: 64 rows x 8 chunks of 16B; 2 chunks/thread
  const int sr2 = tid >> 3;  // 0..31 (row within half)
  const int sp2 = tid & 7;   // chunk position
  // which=1 S-read coords: 64 x-rows x 4 chunks of 16 k
  const int xl = tid >> 2, ch = tid & 3;
  // which=0 S-read coords: 64 x-cols x 4 groups of 16 k-rows
  const int xs = tid & 63, kq = (tid >> 6) * 16;

  __shared__ alignas(16) u16 sA[256 * 64];
  __shared__ alignas(16) u16 sB[64 * 64];
  __shared__ alignas(16) u16 sS[2][64 * 64];  // S tile dbuf (staged ahead)
  __shared__ float lsh[256];
  __shared__ float Lx[64];

  v4f zero = {0.f, 0.f, 0.f, 0.f};
  v4f acc[4][4];
#pragma unroll
  for (int i = 0; i < 4; i++)
#pragma unroll
    for (int j = 0; j < 4; j++) acc[i][j] = zero;

  const float mx = decf(Mst[x0 + (which ? xl : xs)]);
  float lsum = 0.f;

  // stage the S tile for k-step k0 into sS[buf]; rows are x-rows (which=1)
  // or k-rows (which=0); both are 128B-contiguous in global.
  auto stageS = [&](int buf, int k0) {
#pragma unroll
    for (int ii = 0; ii < 2; ii++) {
      int r = ii * 32 + sr2;
      int g2 = sp2 ^ (r & 7);
      const u16* src = which
          ? (Sg + (size_t)(x0 + r) * NNN + k0 + g2 * 8)
          : (Sg + (size_t)(k0 + r) * NNN + x0 + g2 * 8);
      async16(src, &sS[buf][r * 64 + sp2 * 8]);
    }
  };

  stageS(0, 0);  // prologue: S(0); drained by the first barrier
  for (int t = 0; t < 64; t++) {
    const int k0 = t * 64;
    __syncthreads();  // sA/sB reads of step t-1 done; drains pending stages
#pragma unroll
    for (int ii = 0; ii < 8; ii++) {
      int r = wave * 64 + ii * 8 + sr;
      async16(Av + (size_t)r * NNN + k0 + sg * 8, &sA[r * 64 + sp * 8]);
    }
    if (t + 1 < 64) stageS((t + 1) & 1, k0 + 64);
    const u16* sSb = &sS[t & 1][0];
    if (which) {
      // row xl, chunks ch*2 and ch*2+1 (swizzled)
      v8h h0 = *(const v8h*)&sSb[xl * 64 + ((ch * 2) ^ (xl & 7)) * 8];
      v8h h1 = *(const v8h*)&sSb[xl * 64 + ((ch * 2 + 1) ^ (xl & 7)) * 8];
      float e[16];
#pragma unroll
      for (int t2 = 0; t2 < 8; t2++) {
        e[t2] = __expf((float)h0[t2] - mx);
        e[t2 + 8] = __expf((float)h1[t2] - mx);
      }
#pragma unroll
      for (int t2 = 0; t2 < 16; t2++) lsum += e[t2];
      v8h pk0, pk1;
#pragma unroll
      for (int t2 = 0; t2 < 8; t2++) {
        pk0[t2] = (f16)e[t2];
        pk1[t2] = (f16)e[t2 + 8];
      }
      const int g0 = ch * 2;
      *(v8h*)&sB[xl * 64 + (g0 ^ (xl & 7)) * 8] = pk0;
      *(v8h*)&sB[xl * 64 + ((g0 + 1) ^ (xl & 7)) * 8] = pk1;
    } else {
      // column xs of k-rows kq..kq+15 (swizzled element reads)
      float e[16];
      const int cgl = xs >> 3, cil = xs & 7;
#pragma unroll
      for (int t2 = 0; t2 < 16; t2++) {
        int rr = kq + t2;
        u16 hv = sSb[rr * 64 + ((cgl ^ (rr & 7)) << 3) + cil];
        e[t2] = __expf(h2f(hv) - mx);
      }
#pragma unroll
      for (int t2 = 0; t2 < 16; t2++) lsum += e[t2];
      v8h pk0, pk1;
#pragma unroll
      for (int t2 = 0; t2 < 8; t2++) {
        pk0[t2] = (f16)e[t2];
        pk1[t2] = (f16)e[t2 + 8];
      }
      const int g0 = (tid >> 6) * 2;
      *(v8h*)&sB[xs * 64 + (g0 ^ (xs & 7)) * 8] = pk0;
      *(v8h*)&sB[xs * 64 + ((g0 + 1) ^ (xs & 7)) * 8] = pk1;
    }
    __syncthreads();  // drains V(t) + S(t+1); sB visible
#pragma unroll
    for (int s = 0; s < 2; s++) {
      const int pa8 = (s * 4 + q) ^ l7;
      v8h af[4], bfr[4];
#pragma unroll
      for (int i = 0; i < 4; i++)
        af[i] = *(const v8h*)&sA[(wave * 64 + i * 16 + l) * 64 + pa8 * 8];
#pragma unroll
      for (int j = 0; j < 4; j++)
        bfr[j] = *(const v8h*)&sB[(j * 16 + l) * 64 + pa8 * 8];
#pragma unroll
      for (int i = 0; i < 4; i++)
#pragma unroll
        for (int j = 0; j < 4; j++)
          acc[i][j] = __builtin_amdgcn_mfma_f32_16x16x32_f16(af[i], bfr[j],
                                                             acc[i][j], 0, 0, 0);
    }
  }

  // L reduction: 4 threads contribute per x -> Lx = 1/L
  __syncthreads();
  lsh[tid] = lsum;
  __syncthreads();
  if (tid < 64) {
    float t;
    if (which)
      t = (lsh[tid * 4] + lsh[tid * 4 + 1]) + (lsh[tid * 4 + 2] + lsh[tid * 4 + 3]);
    else
      t = (lsh[tid] + lsh[tid + 64]) + (lsh[tid + 128] + lsh[tid + 192]);
    Lx[tid] = 1.0f / t;
  }
  __syncthreads();

#pragma unroll
  for (int i = 0; i < 4; i++)
#pragma unroll
    for (int j = 0; j < 4; j++) {
      const float rl = Lx[j * 16 + l];
#pragma unroll
      for (int r = 0; r < 4; r++) {
        int c = wave * 64 + i * 16 + q * 4 + r;
        Outp[(size_t)c * NNN + x0 + j * 16 + l] = acc[i][j][r] * rl;
      }
    }
}

extern "C" void kernel_launch(void* const* d_in, const int* in_sizes, int n_in,
                              void* d_out, int out_size, void* d_ws,
                              size_t ws_size, hipStream_t stream) {
  const float* a = (const float*)d_in[0];
  const float* b = (const float*)d_in[1];
  const float* W = (const float*)d_in[2];
  float* out = (float*)d_out;

  char* ws = (char*)d_ws;
  u16* Ws = (u16*)(ws);                     // 131072 (256KB rsvd)
  u16* aT = (u16*)(ws + 262144);            // 8388608
  u16* bT = (u16*)(ws + 8650752);           // 8388608
  u16* aCb = (u16*)(ws + 17039360);         // 8388608
  u16* bCb = (u16*)(ws + 25427968);         // 8388608
  u16* ats = (u16*)(ws + 33816576);         // 8388608 (16MB rsvd)
  u32* Mru = (u32*)(ws + 50593792);         // [4][4096] u32 = 65536
  u32* Mcu = (u32*)(ws + 50659328);         // 65536
  u16* Sbuf = (u16*)(ws + 51249152);        // 4 batches fp16 = 134217728
                                            // ends ~185.5 MB

  wsplit<<<dim3(256), 256, 0, stream>>>(W, Ws);
  tsplit<<<dim3(64, 4, 8), 256, 0, stream>>>(a, b, aT, bT, aCb, bCb);
  // a~[n][d] = sum_c aT[n][c] * W[d][c], K=256, out single fp16 pitch 256
  gemm_tn<0><<<dim3(32, 2, 4), 256, 0, stream>>>(
      aT, (long)NNN * 256, 256, 255, Ws, 0, 256, 255, 256,
      ats, (long)NNN * 256, nullptr, nullptr, nullptr);
  hipMemsetAsync(Mru, 0, 131072, stream);  // all 4 batches' Mru+Mcu

  // S[n][m] for all 4 batches in one launch (z = batch)
  gemm_tn<1><<<dim3(32, 32, 4), 256, 0, stream>>>(
      ats, (long)NNN * 256, 256, 255, bT, (long)NNN * 256, 256, 255, 256,
      nullptr, 0, Sbuf, Mru, Mcu);
  // full-K PV + softmax-divide, S staged one step ahead via async16
  pv_part<<<dim3(64, 2, 4), 256, 0, stream>>>(
      aCb, bCb, Sbuf, Mru, Mcu, out, out + 4194304);
}